// Round 1
// baseline (82.529 us; speedup 1.0000x reference)
//
#include <hip/hip_runtime.h>

#define BB 4
#define TT 2048
#define DD 1024
#define EE 8
#define CAP 512
#define NTOK (BB*TT)
#define OUT_HALF ((size_t)NTOK * EE * CAP)   // 33,554,432 floats per tensor

// ---------------- Kernel 1: gating + fused zero-fill of d_out ----------------
// grid = 2048 blocks x 256 threads. One wave (64 lanes) per token (4 tokens/block).
// Each block also zeroes 8192 float4 (128KB) of the output.
__global__ __launch_bounds__(256) void gate_zero_kernel(
    const float* __restrict__ x, const float* __restrict__ w,
    const float* __restrict__ probs,
    int* __restrict__ e0, int* __restrict__ e1, int* __restrict__ r1,
    float* __restrict__ v0, float* __restrict__ v1,
    float4* __restrict__ out4)
{
    // ---- zero-fill slice: block b covers out4[b*8192 .. b*8192+8191] ----
    size_t zbase = (size_t)blockIdx.x * 8192 + threadIdx.x;
    float4 z = make_float4(0.f, 0.f, 0.f, 0.f);
    #pragma unroll
    for (int i = 0; i < 32; ++i) out4[zbase + (size_t)i * 256] = z;

    // ---- gating: one wave per token ----
    const int wave = threadIdx.x >> 6;
    const int lane = threadIdx.x & 63;
    const int token = blockIdx.x * 4 + wave;   // token = b*TT + t
    const float* xt = x + (size_t)token * DD;

    float acc[EE];
    #pragma unroll
    for (int e = 0; e < EE; ++e) acc[e] = 0.f;

    #pragma unroll 4
    for (int i = 0; i < DD / 64; ++i) {
        float xv = xt[i * 64 + lane];
        #pragma unroll
        for (int e = 0; e < EE; ++e)
            acc[e] = fmaf(xv, w[e * DD + i * 64 + lane], acc[e]);
    }
    // wave butterfly reduce each expert accumulator
    #pragma unroll
    for (int e = 0; e < EE; ++e) {
        #pragma unroll
        for (int off = 32; off > 0; off >>= 1)
            acc[e] += __shfl_xor(acc[e], off, 64);
    }

    if (lane == 0) {
        float mx = acc[0];
        #pragma unroll
        for (int e = 1; e < EE; ++e) mx = fmaxf(mx, acc[e]);
        float ex[EE]; float Z = 0.f;
        #pragma unroll
        for (int e = 0; e < EE; ++e) { ex[e] = expf(acc[e] - mx); Z += ex[e]; }
        // top-2 (ties -> lower index first, matching jax.lax.top_k)
        int i0 = 0;
        #pragma unroll
        for (int e = 1; e < EE; ++e) if (ex[e] > ex[i0]) i0 = e;
        int i1 = (i0 == 0) ? 1 : 0;
        #pragma unroll
        for (int e = 0; e < EE; ++e) if (e != i0 && ex[e] > ex[i1]) i1 = e;
        float t0 = ex[i0] / Z, t1 = ex[i1] / Z;
        float den = fmaxf(t0 + t1, 1e-9f);
        float g0 = t0 / den, g1 = t1 / den;
        // stochastic threshold for rank 1: probs[1,b,t] < g1 / 0.2
        float p1 = probs[NTOK + token];
        int route = (p1 < g1 / 0.2f) ? 1 : 0;
        e0[token] = i0; e1[token] = i1; r1[token] = route;
        v0[token] = g0; v1[token] = g1;
    }
}

// ---------------- Kernel 2: per-batch capacity scan + scatter ----------------
// grid = 4 blocks (one per batch) x 1024 threads (16 waves).
// Tokens processed in two chunks of 1024 with carried per-expert counters.
__global__ __launch_bounds__(1024) void scan_scatter_kernel(
    const int* __restrict__ e0, const int* __restrict__ e1, const int* __restrict__ r1,
    const float* __restrict__ v0, const float* __restrict__ v1,
    float* __restrict__ dispatch, float* __restrict__ combine)
{
    const int b = blockIdx.x;
    const int tid = threadIdx.x;
    const int wave = tid >> 6;
    const int lane = tid & 63;

    __shared__ int cnt[16][EE];
    __shared__ int off[16][EE];
    __shared__ int base[EE];

    if (tid < EE) base[tid] = 0;
    __syncthreads();

    for (int k = 0; k < 2; ++k) {
        for (int chunk = 0; chunk < 2; ++chunk) {
            const int t = chunk * 1024 + tid;
            const int gidx = b * TT + t;
            int e; float g; bool active;
            if (k == 0) { e = e0[gidx]; g = v0[gidx]; active = true; }
            else        { e = e1[gidx]; g = v1[gidx]; active = (r1[gidx] != 0); }

            if (tid < 16 * EE) cnt[tid >> 3][tid & 7] = 0;
            __syncthreads();

            // match-any over 3 expert bits, restricted to active lanes
            unsigned long long act = __ballot(active);
            unsigned long long m = act;
            #pragma unroll
            for (int bit = 0; bit < 3; ++bit) {
                unsigned long long bm = __ballot((e >> bit) & 1);
                m &= ((e >> bit) & 1) ? bm : ~bm;
            }
            int rank = __popcll(m & ((1ull << lane) - 1ull));
            if (active && rank == 0) cnt[wave][e] = __popcll(m);
            __syncthreads();

            // exclusive scan of wave counts per expert (8 threads, 16 steps)
            if (tid < EE) {
                int run = base[tid];
                #pragma unroll
                for (int w = 0; w < 16; ++w) { off[w][tid] = run; run += cnt[w][tid]; }
                base[tid] = run;
            }
            __syncthreads();

            if (active) {
                int pos = off[wave][e] + rank;
                if (pos < CAP) {
                    size_t oi = (((size_t)gidx) * EE + e) * CAP + pos;
                    dispatch[oi] = 1.0f;
                    combine[oi]  = g;
                }
            }
            __syncthreads();
        }
        if (k == 0) {
            // prev[e] = number of kept rank-0 tokens = min(count, CAP)
            if (tid < EE) base[tid] = min(base[tid], CAP);
            __syncthreads();
        }
    }
}

extern "C" void kernel_launch(void* const* d_in, const int* in_sizes, int n_in,
                              void* d_out, int out_size, void* d_ws, size_t ws_size,
                              hipStream_t stream) {
    const float* x     = (const float*)d_in[0];
    const float* w     = (const float*)d_in[1];
    const float* probs = (const float*)d_in[2];
    float* out = (float*)d_out;

    int*   e0 = (int*)d_ws;
    int*   e1 = e0 + NTOK;
    int*   r1 = e1 + NTOK;
    float* v0 = (float*)(r1 + NTOK);
    float* v1 = v0 + NTOK;

    gate_zero_kernel<<<2048, 256, 0, stream>>>(x, w, probs, e0, e1, r1, v0, v1,
                                               (float4*)out);
    scan_scatter_kernel<<<4, 1024, 0, stream>>>(e0, e1, r1, v0, v1,
                                                out, out + OUT_HALF);
}

// Round 2
// 68.192 us; speedup vs baseline: 1.2102x; 1.2102x over previous
//
#include <hip/hip_runtime.h>

#define BB 4
#define TT 2048
#define DD 1024
#define EE 8
#define CAP 512
#define NTOK (BB*TT)
#define OUT_HALF ((size_t)NTOK * EE * CAP)   // 33,554,432 floats per tensor

// ---------------- Kernel 1: gating ----------------
// grid = 2048 blocks x 256 threads. One wave (64 lanes) per token.
__global__ __launch_bounds__(256) void gate_kernel(
    const float* __restrict__ x, const float* __restrict__ w,
    const float* __restrict__ probs,
    int* __restrict__ e0, int* __restrict__ e1, int* __restrict__ r1,
    float* __restrict__ v0, float* __restrict__ v1)
{
    const int wave = threadIdx.x >> 6;
    const int lane = threadIdx.x & 63;
    const int token = blockIdx.x * 4 + wave;   // token = b*TT + t
    const float* xt = x + (size_t)token * DD;

    float acc[EE];
    #pragma unroll
    for (int e = 0; e < EE; ++e) acc[e] = 0.f;

    #pragma unroll 4
    for (int i = 0; i < DD / 64; ++i) {
        float xv = xt[i * 64 + lane];
        #pragma unroll
        for (int e = 0; e < EE; ++e)
            acc[e] = fmaf(xv, w[e * DD + i * 64 + lane], acc[e]);
    }
    #pragma unroll
    for (int e = 0; e < EE; ++e) {
        #pragma unroll
        for (int off = 32; off > 0; off >>= 1)
            acc[e] += __shfl_xor(acc[e], off, 64);
    }

    if (lane == 0) {
        float mx = acc[0];
        #pragma unroll
        for (int e = 1; e < EE; ++e) mx = fmaxf(mx, acc[e]);
        float ex[EE]; float Z = 0.f;
        #pragma unroll
        for (int e = 0; e < EE; ++e) { ex[e] = expf(acc[e] - mx); Z += ex[e]; }
        int i0 = 0;
        #pragma unroll
        for (int e = 1; e < EE; ++e) if (ex[e] > ex[i0]) i0 = e;
        int i1 = (i0 == 0) ? 1 : 0;
        #pragma unroll
        for (int e = 0; e < EE; ++e) if (e != i0 && ex[e] > ex[i1]) i1 = e;
        float t0 = ex[i0] / Z, t1 = ex[i1] / Z;
        float den = fmaxf(t0 + t1, 1e-9f);
        float g0 = t0 / den, g1 = t1 / den;
        float p1 = probs[NTOK + token];
        int route = (p1 < g1 / 0.2f) ? 1 : 0;
        e0[token] = i0; e1[token] = i1; r1[token] = route;
        v0[token] = g0; v1[token] = g1;
    }
}

// ---------------- Kernel 2: per-batch capacity scan ----------------
// grid = 4 blocks (one per batch) x 1024 threads (16 waves).
// Writes flat targets t0/t1 = e*CAP+pos (or -1 if dropped) IN PLACE over e0/e1.
__global__ __launch_bounds__(1024) void scan_kernel(
    int* __restrict__ e0, int* __restrict__ e1, const int* __restrict__ r1,
    const float* __restrict__ v0, const float* __restrict__ v1)
{
    const int b = blockIdx.x;
    const int tid = threadIdx.x;
    const int wave = tid >> 6;
    const int lane = tid & 63;

    __shared__ int cnt[16][EE];
    __shared__ int off[16][EE];
    __shared__ int base[EE];

    if (tid < EE) base[tid] = 0;
    __syncthreads();

    for (int k = 0; k < 2; ++k) {
        for (int chunk = 0; chunk < 2; ++chunk) {
            const int t = chunk * 1024 + tid;
            const int gidx = b * TT + t;
            int e; bool active;
            if (k == 0) { e = e0[gidx]; active = true; }
            else        { e = e1[gidx]; active = (r1[gidx] != 0); }

            if (tid < 16 * EE) cnt[tid >> 3][tid & 7] = 0;
            __syncthreads();

            // match-any over 3 expert bits, restricted to active lanes
            unsigned long long act = __ballot(active);
            unsigned long long m = act;
            #pragma unroll
            for (int bit = 0; bit < 3; ++bit) {
                unsigned long long bm = __ballot((e >> bit) & 1);
                m &= ((e >> bit) & 1) ? bm : ~bm;
            }
            int rank = __popcll(m & ((1ull << lane) - 1ull));
            if (active && rank == 0) cnt[wave][e] = __popcll(m);
            __syncthreads();

            // exclusive scan of wave counts per expert (8 threads, 16 steps)
            if (tid < EE) {
                int run = base[tid];
                #pragma unroll
                for (int w = 0; w < 16; ++w) { off[w][tid] = run; run += cnt[w][tid]; }
                base[tid] = run;
            }
            __syncthreads();

            int tgt = -1;
            if (active) {
                int pos = off[wave][e] + rank;
                if (pos < CAP) tgt = e * CAP + pos;
            }
            if (k == 0) e0[gidx] = tgt; else e1[gidx] = tgt;
            __syncthreads();
        }
        if (k == 0) {
            // prev[e] = number of kept rank-0 tokens = min(count, CAP)
            if (tid < EE) base[tid] = min(base[tid], CAP);
            __syncthreads();
        }
    }
}

// ---------------- Kernel 3: fused zero-fill + scatter (pure streaming) -------
// grid = 8192 blocks (one per token) x 256 threads. Each block writes the
// token's [E,C]=4096-float row in BOTH tensors: 2048 float4 coalesced stores,
// nonzeros inserted branchlessly via per-component compares.
__global__ __launch_bounds__(256) void fill_scatter_kernel(
    const int* __restrict__ t0, const int* __restrict__ t1,
    const float* __restrict__ v0, const float* __restrict__ v1,
    float4* __restrict__ out)
{
    const int token = blockIdx.x;
    const int tid = threadIdx.x;
    const int a0 = t0[token];
    const int a1 = t1[token];
    const float g0 = v0[token];
    const float g1 = v1[token];

    float4* drow = out + (size_t)token * 1024;                 // dispatch row
    float4* crow = out + (OUT_HALF / 4) + (size_t)token * 1024; // combine row

    #pragma unroll
    for (int i = 0; i < 4; ++i) {
        const int f = i * 1024 + tid * 4;   // flat float index within row
        float4 d, c;
        d.x = (f + 0 == a0 || f + 0 == a1) ? 1.f : 0.f;
        d.y = (f + 1 == a0 || f + 1 == a1) ? 1.f : 0.f;
        d.z = (f + 2 == a0 || f + 2 == a1) ? 1.f : 0.f;
        d.w = (f + 3 == a0 || f + 3 == a1) ? 1.f : 0.f;
        c.x = (f + 0 == a0) ? g0 : ((f + 0 == a1) ? g1 : 0.f);
        c.y = (f + 1 == a0) ? g0 : ((f + 1 == a1) ? g1 : 0.f);
        c.z = (f + 2 == a0) ? g0 : ((f + 2 == a1) ? g1 : 0.f);
        c.w = (f + 3 == a0) ? g0 : ((f + 3 == a1) ? g1 : 0.f);
        drow[i * 256 + tid] = d;
        crow[i * 256 + tid] = c;
    }
}

extern "C" void kernel_launch(void* const* d_in, const int* in_sizes, int n_in,
                              void* d_out, int out_size, void* d_ws, size_t ws_size,
                              hipStream_t stream) {
    const float* x     = (const float*)d_in[0];
    const float* w     = (const float*)d_in[1];
    const float* probs = (const float*)d_in[2];
    float* out = (float*)d_out;

    int*   e0 = (int*)d_ws;
    int*   e1 = e0 + NTOK;
    int*   r1 = e1 + NTOK;
    float* v0 = (float*)(r1 + NTOK);
    float* v1 = v0 + NTOK;

    gate_kernel<<<2048, 256, 0, stream>>>(x, w, probs, e0, e1, r1, v0, v1);
    scan_kernel<<<4, 1024, 0, stream>>>(e0, e1, r1, v0, v1);
    fill_scatter_kernel<<<8192, 256, 0, stream>>>(e0, e1, v0, v1, (float4*)out);
}